// Round 2
// baseline (138.177 us; speedup 1.0000x reference)
//
#include <hip/hip_runtime.h>
#include <hip/hip_bf16.h>
#include <stdint.h>

typedef __attribute__((ext_vector_type(8))) __bf16 bf16x8;
typedef __attribute__((ext_vector_type(4))) float f32x4;

__device__ __forceinline__ unsigned short f2bf(float f) {
    unsigned u = __builtin_bit_cast(unsigned, f);
    return (unsigned short)((u + 0x7fffu + ((u >> 16) & 1u)) >> 16);  // RNE
}

__device__ __forceinline__ void glds16(const void* g, void* l) {
    __builtin_amdgcn_global_load_lds(
        (const __attribute__((address_space(1))) unsigned int*)(uintptr_t)g,
        (__attribute__((address_space(3))) unsigned int*)l, 16, 0, 0);
}

// ---------------------------------------------------------------------------
// Kernel 1: build G01[b][a0a1][o01][q] = F0[a0,o0,r0]*F1[a1,o1,r1]   (q=r0*2+r1)
//           and H23[b][o23][a2a3][q] = sum_{r2,r3} F2[a2,o2,r2]*F3[a3,o3,r3]
//                                      * core_flat[b, r3*8+r2*4+r1*2+r0]
// factors layout: [b][j][i][o][r] strides b:512 j:128 i:16 o:2 r:1
// ---------------------------------------------------------------------------
__global__ __launch_bounds__(256) void prep_tables(const float* __restrict__ factors,
                                                   const float* __restrict__ cores,
                                                   float* __restrict__ G01,
                                                   float* __restrict__ H23) {
    int idx = blockIdx.x * 256 + threadIdx.x;   // 0 .. 131071
    if (idx < 65536) {
        int q = idx & 3, o01 = (idx >> 2) & 63, a01 = (idx >> 8) & 63, b = idx >> 14;
        int r0 = q >> 1, r1 = q & 1;
        int o0 = o01 >> 3, o1 = o01 & 7, a0 = a01 >> 3, a1 = a01 & 7;
        G01[idx] = factors[b*512 +   0 + a0*16 + o0*2 + r0]
                 * factors[b*512 + 128 + a1*16 + o1*2 + r1];
    } else {
        int j = idx - 65536;
        int q = j & 3, a23 = (j >> 2) & 63, o23 = (j >> 8) & 63, b = j >> 14;
        int r0 = q >> 1, r1 = q & 1;
        int o2 = o23 >> 3, o3 = o23 & 7, a2 = a23 >> 3, a3 = a23 & 7;
        float s = 0.f;
#pragma unroll
        for (int r2 = 0; r2 < 2; ++r2)
#pragma unroll
            for (int r3 = 0; r3 < 2; ++r3)
                s += factors[b*512 + 256 + a2*16 + o2*2 + r2]
                   * factors[b*512 + 384 + a3*16 + o3*2 + r3]
                   * cores[b*16 + r3*8 + r2*4 + r1*2 + r0];
        H23[j] = s;   // j == ((b*64 + o23)*64 + a23)*4 + q
    }
}

// ---------------------------------------------------------------------------
// Kernel 2: convert x (f32) -> bf16
// ---------------------------------------------------------------------------
__global__ __launch_bounds__(256) void cvt_bf16(const float4* __restrict__ in,
                                                ushort4* __restrict__ out) {
    int i = blockIdx.x * 256 + threadIdx.x;     // exactly 1048576 threads
    float4 v = in[i];
    ushort4 o;
    o.x = f2bf(v.x); o.y = f2bf(v.y); o.z = f2bf(v.z); o.w = f2bf(v.w);
    out[i] = o;
}

// ---------------------------------------------------------------------------
// Kernel 3: Wt[o][i] (bf16, row-major, stride 4096)
//   o = o01*64 + o23, i = a01*64 + a23
//   Wt = sum_{b,q} G01[b][a01][o01][q] * H23[b][o23][a23][q]
// ---------------------------------------------------------------------------
__global__ __launch_bounds__(256) void build_w(const float* __restrict__ G01,
                                               const float* __restrict__ H23,
                                               unsigned short* __restrict__ Wt) {
    __shared__ float gs[2048];                  // [b][a'(2)][o01(64)][q(4)]
    const int w = blockIdx.x;
    const int pgrp = w & 15, lgrp = w >> 4;     // lgrp 0..31
    const int tid = threadIdx.x;
#pragma unroll
    for (int rep = 0; rep < 2; ++rep) {
        int j = (rep * 256 + tid) * 4;          // flat gs index
        int b = j >> 9, a = (j >> 8) & 1, rest = j & 255;
        *(float4*)&gs[j] = *(const float4*)&G01[((b * 64 + lgrp * 2 + a) << 8) + rest];
    }
    __syncthreads();
    const int p = pgrp * 256 + tid;
    const int o23 = p >> 6, a23 = p & 63;
    const float4 h0 = *(const float4*)&H23[(( 0 + o23) * 64 + a23) * 4];
    const float4 h1 = *(const float4*)&H23[((64 + o23) * 64 + a23) * 4];
    const float4 h2 = *(const float4*)&H23[((128 + o23) * 64 + a23) * 4];
    const float4 h3 = *(const float4*)&H23[((192 + o23) * 64 + a23) * 4];
    for (int it = 0; it < 128; ++it) {
        int a = it >> 6, o01 = it & 63;
        const float* gp = &gs[a * 256 + (o01 << 2)];
        float v = gp[0]    * h0.x + gp[1]    * h0.y + gp[2]    * h0.z + gp[3]    * h0.w
                + gp[512]  * h1.x + gp[513]  * h1.y + gp[514]  * h1.z + gp[515]  * h1.w
                + gp[1024] * h2.x + gp[1025] * h2.y + gp[1026] * h2.z + gp[1027] * h2.w
                + gp[1536] * h3.x + gp[1537] * h3.y + gp[1538] * h3.z + gp[1539] * h3.w;
        int a01 = lgrp * 2 + a;
        Wt[(size_t)(o01 * 64 + o23) * 4096 + (a01 * 64 + a23)] = f2bf(v);
    }
}

// ---------------------------------------------------------------------------
// Kernel 4a: zero C (harness poisons d_out; atomics below need zeros)
// ---------------------------------------------------------------------------
__global__ __launch_bounds__(256) void zero_f32(float4* __restrict__ p, int n4) {
    int i = blockIdx.x * 256 + threadIdx.x;
    int stride = gridDim.x * 256;
    for (; i < n4; i += stride) p[i] = float4{0.f, 0.f, 0.f, 0.f};
}

// ---------------------------------------------------------------------------
// Kernel 4b: C[1024][4096] += A[1024][4096] * Wt^T over K-chunk ks.
// Split-K x4: grid 1024 blocks (4/CU -> wave-level latency hiding), each block
// contracts K in [ks*1024,(ks+1)*1024), epilogue = global f32 atomicAdd.
// m97-structure otherwise: 128x128 tile, BK=32, 4 waves (2x2), 16x16x32 MFMA,
// global_load_lds width-16 staging, 2-barrier main loop.
// ---------------------------------------------------------------------------
__global__ __launch_bounds__(256) void gemm_bt_sk(const unsigned short* __restrict__ A,
                                                  const unsigned short* __restrict__ Bt,
                                                  float* __restrict__ C) {
    constexpr int K = 4096;
    constexpr int N = 4096;
    constexpr int KCH = 1024;                   // K-chunk per block
    __shared__ alignas(16) unsigned short As[128 * 32];
    __shared__ alignas(16) unsigned short Bs[128 * 32];
    const int tid = threadIdx.x;
    const int bn = blockIdx.x & 31;             // 0..31
    const int bm = (blockIdx.x >> 5) & 7;       // 0..7
    const int ks = blockIdx.x >> 8;             // 0..3
    const int wid = tid >> 6, lane = tid & 63;
    const int wm = wid >> 1, wn = wid & 1;

    // staging: thread t loads 8 bf16 from row (t>>2), col ((t&3)*8) of the tile
    const int srow = tid >> 2;
    const int scol = (tid & 3) << 3;
    const unsigned short* gA0 = A  + (size_t)(bm * 128 + srow) * K + ks * KCH + scol;
    const unsigned short* gB0 = Bt + (size_t)(bn * 128 + srow) * K + ks * KCH + scol;
    char* lA = (char*)As + wid * 1024;          // wave-uniform LDS base
    char* lB = (char*)Bs + wid * 1024;

    const int fr = lane & 15, fh = lane >> 4;
    const char* pA = (const char*)As + (wm * 64 + fr) * 64 + fh * 16;
    const char* pB = (const char*)Bs + (wn * 64 + fr) * 64 + fh * 16;

    f32x4 acc[4][4] = {};

    for (int kt = 0; kt < KCH; kt += 32) {
        glds16(gA0 + kt, lA);
        glds16(gA0 + 64 * K + kt, lA + 4096);
        glds16(gB0 + kt, lB);
        glds16(gB0 + 64 * K + kt, lB + 4096);
        __syncthreads();                         // drains vmcnt -> tiles ready
        bf16x8 af[4], bfr[4];
#pragma unroll
        for (int i = 0; i < 4; ++i) af[i]  = *(const bf16x8*)(pA + i * 1024);
#pragma unroll
        for (int i = 0; i < 4; ++i) bfr[i] = *(const bf16x8*)(pB + i * 1024);
#pragma unroll
        for (int mi = 0; mi < 4; ++mi)
#pragma unroll
            for (int ni = 0; ni < 4; ++ni)
                acc[mi][ni] = __builtin_amdgcn_mfma_f32_16x16x32_bf16(
                    af[mi], bfr[ni], acc[mi][ni], 0, 0, 0);
        __syncthreads();                         // all reads done before next stage
    }

    const int crow0 = bm * 128 + wm * 64 + fh * 4;
    const int ccol0 = bn * 128 + wn * 64 + fr;
#pragma unroll
    for (int mi = 0; mi < 4; ++mi)
#pragma unroll
        for (int ni = 0; ni < 4; ++ni)
#pragma unroll
            for (int j = 0; j < 4; ++j)
                atomicAdd(&C[(size_t)(crow0 + mi * 16 + j) * N + (ccol0 + ni * 16)],
                          acc[mi][ni][j]);
}

// ---------------------------------------------------------------------------
extern "C" void kernel_launch(void* const* d_in, const int* in_sizes, int n_in,
                              void* d_out, int out_size, void* d_ws, size_t ws_size,
                              hipStream_t stream) {
    const float* inputs  = (const float*)d_in[0];   // [1024, 4096] f32
    const float* cores   = (const float*)d_in[1];   // [4, 16] f32
    const float* factors = (const float*)d_in[2];   // [4,4,8,8,2] f32
    float* out = (float*)d_out;                     // [1024, 4096] f32

    char* ws = (char*)d_ws;
    unsigned short* xb = (unsigned short*)ws;                       //  8 MB bf16 x
    unsigned short* Wt = (unsigned short*)(ws + (8u << 20));        // 32 MB bf16 W^T
    float* G01 = (float*)(ws + (40u << 20));                        // 256 KB
    float* H23 = G01 + 65536;                                       // 256 KB

    prep_tables<<<512, 256, 0, stream>>>(factors, cores, G01, H23);
    cvt_bf16<<<4096, 256, 0, stream>>>((const float4*)inputs, (ushort4*)xb);
    build_w<<<512, 256, 0, stream>>>(G01, H23, Wt);
    zero_f32<<<2048, 256, 0, stream>>>((float4*)out, out_size / 4);
    gemm_bt_sk<<<1024, 256, 0, stream>>>(xb, Wt, out);
}

// Round 3
// 123.254 us; speedup vs baseline: 1.1211x; 1.1211x over previous
//
#include <hip/hip_runtime.h>
#include <hip/hip_bf16.h>
#include <stdint.h>

typedef __attribute__((ext_vector_type(8))) __bf16 bf16x8;
typedef __attribute__((ext_vector_type(4))) float f32x4;
typedef __attribute__((ext_vector_type(8))) unsigned short u16x8;

__device__ __forceinline__ unsigned short f2bf(float f) {
    unsigned u = __builtin_bit_cast(unsigned, f);
    return (unsigned short)((u + 0x7fffu + ((u >> 16) & 1u)) >> 16);  // RNE
}

__device__ __forceinline__ void glds16(const void* g, void* l) {
    __builtin_amdgcn_global_load_lds(
        (const __attribute__((address_space(1))) unsigned int*)(uintptr_t)g,
        (__attribute__((address_space(3))) unsigned int*)l, 16, 0, 0);
}

// ---------------------------------------------------------------------------
// Kernel 1: build G01[b][a0a1][o01][q] = F0[a0,o0,r0]*F1[a1,o1,r1]   (q=r0*2+r1)
//           and H23[b][o23][a2a3][q] = sum_{r2,r3} F2[a2,o2,r2]*F3[a3,o3,r3]
//                                      * core_flat[b, r3*8+r2*4+r1*2+r0]
// ---------------------------------------------------------------------------
__global__ __launch_bounds__(256) void prep_tables(const float* __restrict__ factors,
                                                   const float* __restrict__ cores,
                                                   float* __restrict__ G01,
                                                   float* __restrict__ H23) {
    int idx = blockIdx.x * 256 + threadIdx.x;   // 0 .. 131071
    if (idx < 65536) {
        int q = idx & 3, o01 = (idx >> 2) & 63, a01 = (idx >> 8) & 63, b = idx >> 14;
        int r0 = q >> 1, r1 = q & 1;
        int o0 = o01 >> 3, o1 = o01 & 7, a0 = a01 >> 3, a1 = a01 & 7;
        G01[idx] = factors[b*512 +   0 + a0*16 + o0*2 + r0]
                 * factors[b*512 + 128 + a1*16 + o1*2 + r1];
    } else {
        int j = idx - 65536;
        int q = j & 3, a23 = (j >> 2) & 63, o23 = (j >> 8) & 63, b = j >> 14;
        int r0 = q >> 1, r1 = q & 1;
        int o2 = o23 >> 3, o3 = o23 & 7, a2 = a23 >> 3, a3 = a23 & 7;
        float s = 0.f;
#pragma unroll
        for (int r2 = 0; r2 < 2; ++r2)
#pragma unroll
            for (int r3 = 0; r3 < 2; ++r3)
                s += factors[b*512 + 256 + a2*16 + o2*2 + r2]
                   * factors[b*512 + 384 + a3*16 + o3*2 + r3]
                   * cores[b*16 + r3*8 + r2*4 + r1*2 + r0];
        H23[j] = s;   // j == ((b*64 + o23)*64 + a23)*4 + q
    }
}

// ---------------------------------------------------------------------------
// Kernel 2: convert x (f32) -> bf16
// ---------------------------------------------------------------------------
__global__ __launch_bounds__(256) void cvt_bf16(const float4* __restrict__ in,
                                                ushort4* __restrict__ out) {
    int i = blockIdx.x * 256 + threadIdx.x;     // exactly 1048576 threads
    float4 v = in[i];
    ushort4 o;
    o.x = f2bf(v.x); o.y = f2bf(v.y); o.z = f2bf(v.z); o.w = f2bf(v.w);
    out[i] = o;
}

// ---------------------------------------------------------------------------
// Kernel 3: Wt[o][i] (bf16), o = o01*64+o23, i = a01*64+a23.
// v2: accumulate per-thread as before, but buffer the block's 256x128 output
// in LDS and store with coalesced 16B writes (was: 16.7M scalar 2B stores).
// ---------------------------------------------------------------------------
__global__ __launch_bounds__(256) void build_w(const float* __restrict__ G01,
                                               const float* __restrict__ H23,
                                               unsigned short* __restrict__ Wt) {
    __shared__ float gs[2048];                   // [b][a'(2)][o01(64)][q(4)]
    __shared__ unsigned short lbuf[256 * 128];   // [o-row(256)][i-col(128)]
    const int bid = blockIdx.x;
    const int pgrp = bid & 15, lgrp = bid >> 4;  // lgrp 0..31
    const int tid = threadIdx.x;
#pragma unroll
    for (int rep = 0; rep < 2; ++rep) {
        int j = (rep * 256 + tid) * 4;
        int b = j >> 9, a = (j >> 8) & 1, rest = j & 255;
        *(float4*)&gs[j] = *(const float4*)&G01[((b * 64 + lgrp * 2 + a) << 8) + rest];
    }
    __syncthreads();
    const int o23l = tid >> 6;                   // 0..3
    const int o23 = pgrp * 4 + o23l;
    const int a23 = tid & 63;
    const float4 h0 = *(const float4*)&H23[(( 0 + o23) * 64 + a23) * 4];
    const float4 h1 = *(const float4*)&H23[((64 + o23) * 64 + a23) * 4];
    const float4 h2 = *(const float4*)&H23[((128 + o23) * 64 + a23) * 4];
    const float4 h3 = *(const float4*)&H23[((192 + o23) * 64 + a23) * 4];
    for (int it = 0; it < 128; ++it) {
        int a = it >> 6, o01 = it & 63;
        const float* gp = &gs[a * 256 + (o01 << 2)];
        float v = gp[0]    * h0.x + gp[1]    * h0.y + gp[2]    * h0.z + gp[3]    * h0.w
                + gp[512]  * h1.x + gp[513]  * h1.y + gp[514]  * h1.z + gp[515]  * h1.w
                + gp[1024] * h2.x + gp[1025] * h2.y + gp[1026] * h2.z + gp[1027] * h2.w
                + gp[1536] * h3.x + gp[1537] * h3.y + gp[1538] * h3.z + gp[1539] * h3.w;
        lbuf[(o01 * 4 + o23l) * 128 + a * 64 + a23] = f2bf(v);   // 128B/wave, 2-way free
    }
    __syncthreads();
    // store: 4096 x 16B chunks; thread t does chunks {t + 256*j}
#pragma unroll
    for (int j = 0; j < 16; ++j) {
        int ch = j * 256 + tid;
        int row = ch >> 4, cc = ch & 15;                         // row 0..255, chunk 0..15
        int o = (row >> 2) * 64 + pgrp * 4 + (row & 3);
        *(u16x8*)&Wt[(size_t)o * 4096 + lgrp * 128 + cc * 8] =
            *(const u16x8*)&lbuf[row * 128 + cc * 8];
    }
}

// ---------------------------------------------------------------------------
// Kernel 4a: zero C (atomics epilogue needs zeros; harness poisons d_out)
// ---------------------------------------------------------------------------
__global__ __launch_bounds__(256) void zero_f32(float4* __restrict__ p, int n4) {
    int i = blockIdx.x * 256 + threadIdx.x;
    int stride = gridDim.x * 256;
    for (; i < n4; i += stride) p[i] = float4{0.f, 0.f, 0.f, 0.f};
}

// ---------------------------------------------------------------------------
// Kernel 4b: C += A * Wt^T over K-chunk. v3 geometry:
//   block-tile 256(M) x 128(N), BK=32, 4 waves (2M x 2N), wave-tile 128x64
//   -> FLOP/LDS-byte 42.7 (was 32); acc 8x4 f32x4.
// LDS bank conflicts removed via source-side XOR chunk swizzle (rule 21):
//   physical 16B chunk p of row r holds logical chunk p ^ ((r>>1)&3);
//   glds16 dest stays linear, global src pre-swizzled, reads XOR the same key.
//   Read key is lane-only ((fr>>1)&3) since frag offsets are multiples of 16 rows.
// Split-K x4: grid 512 (2 blocks/CU), f32 atomicAdd epilogue.
// ---------------------------------------------------------------------------
__global__ __launch_bounds__(256, 2) void gemm_bt_sk(const unsigned short* __restrict__ A,
                                                     const unsigned short* __restrict__ Bt,
                                                     float* __restrict__ C) {
    constexpr int K = 4096;
    constexpr int N = 4096;
    constexpr int KCH = 1024;                    // K per block
    __shared__ alignas(16) unsigned short As[256 * 32];   // 16 KB
    __shared__ alignas(16) unsigned short Bs[128 * 32];   //  8 KB
    const int tid = threadIdx.x;
    const int bn = blockIdx.x & 31;              // 0..31
    const int bm = (blockIdx.x >> 5) & 3;        // 0..3
    const int ks = blockIdx.x >> 7;              // 0..3
    const int lane = tid & 63, w = tid >> 6;
    const int wm = w >> 1, wn = w & 1;

    // --- staging: A = 1024 16B-chunk slots (4/thread), B = 512 (2/thread) ---
    const unsigned short* gA[4]; const unsigned short* gB[2];
    char* lA[4]; char* lB[2];
#pragma unroll
    for (int i = 0; i < 4; ++i) {
        int cs = w * 256 + i * 64 + lane;        // slot: row=cs>>2, phys chunk=cs&3
        int row = cs >> 2;
        int c = (cs & 3) ^ ((row >> 1) & 3);     // logical chunk to fetch
        gA[i] = A + (size_t)(bm * 256 + row) * K + ks * KCH + c * 8;
        lA[i] = (char*)As + w * 4096 + i * 1024; // wave-uniform (+lane*16 by HW)
    }
#pragma unroll
    for (int i = 0; i < 2; ++i) {
        int cs = w * 128 + i * 64 + lane;
        int row = cs >> 2;
        int c = (cs & 3) ^ ((row >> 1) & 3);
        gB[i] = Bt + (size_t)(bn * 128 + row) * K + ks * KCH + c * 8;
        lB[i] = (char*)Bs + w * 2048 + i * 1024;
    }

    // --- fragment read pointers (swizzled) ---
    const int fr = lane & 15, fh = lane >> 4;
    const int swz = (fr >> 1) & 3;
    const char* pA = (const char*)As + (wm * 128 + fr) * 64 + ((fh ^ swz) << 4);
    const char* pB = (const char*)Bs + (wn * 64 + fr) * 64 + ((fh ^ swz) << 4);

    f32x4 acc[8][4] = {};

    for (int kt = 0; kt < KCH; kt += 32) {
#pragma unroll
        for (int i = 0; i < 4; ++i) glds16(gA[i] + kt, lA[i]);
#pragma unroll
        for (int i = 0; i < 2; ++i) glds16(gB[i] + kt, lB[i]);
        __syncthreads();                         // drains vmcnt -> tiles ready
        bf16x8 af[8], bfr[4];
#pragma unroll
        for (int m = 0; m < 8; ++m) af[m]  = *(const bf16x8*)(pA + m * 1024);
#pragma unroll
        for (int n = 0; n < 4; ++n) bfr[n] = *(const bf16x8*)(pB + n * 1024);
#pragma unroll
        for (int m = 0; m < 8; ++m)
#pragma unroll
            for (int n = 0; n < 4; ++n)
                acc[m][n] = __builtin_amdgcn_mfma_f32_16x16x32_bf16(
                    af[m], bfr[n], acc[m][n], 0, 0, 0);
        __syncthreads();                         // all reads done before next stage
    }

    const int crow0 = bm * 256 + wm * 128 + fh * 4;
    const int ccol0 = bn * 128 + wn * 64 + fr;
#pragma unroll
    for (int m = 0; m < 8; ++m)
#pragma unroll
        for (int n = 0; n < 4; ++n)
#pragma unroll
            for (int j = 0; j < 4; ++j)
                atomicAdd(&C[(size_t)(crow0 + m * 16 + j) * N + (ccol0 + n * 16)],
                          acc[m][n][j]);
}

// ---------------------------------------------------------------------------
extern "C" void kernel_launch(void* const* d_in, const int* in_sizes, int n_in,
                              void* d_out, int out_size, void* d_ws, size_t ws_size,
                              hipStream_t stream) {
    const float* inputs  = (const float*)d_in[0];   // [1024, 4096] f32
    const float* cores   = (const float*)d_in[1];   // [4, 16] f32
    const float* factors = (const float*)d_in[2];   // [4,4,8,8,2] f32
    float* out = (float*)d_out;                     // [1024, 4096] f32

    char* ws = (char*)d_ws;
    unsigned short* xb = (unsigned short*)ws;                       //  8 MB bf16 x
    unsigned short* Wt = (unsigned short*)(ws + (8u << 20));        // 32 MB bf16 W^T
    float* G01 = (float*)(ws + (40u << 20));                        // 256 KB
    float* H23 = G01 + 65536;                                       // 256 KB

    prep_tables<<<512, 256, 0, stream>>>(factors, cores, G01, H23);
    cvt_bf16<<<4096, 256, 0, stream>>>((const float4*)inputs, (ushort4*)xb);
    build_w<<<512, 256, 0, stream>>>(G01, H23, Wt);
    zero_f32<<<2048, 256, 0, stream>>>((float4*)out, out_size / 4);
    gemm_bt_sk<<<512, 256, 0, stream>>>(xb, Wt, out);
}

// Round 4
// 87.239 us; speedup vs baseline: 1.5839x; 1.4128x over previous
//
#include <hip/hip_runtime.h>
#include <hip/hip_bf16.h>
#include <stdint.h>

typedef __attribute__((ext_vector_type(8))) __bf16 bf16x8;
typedef __attribute__((ext_vector_type(4))) float f32x4;
typedef __attribute__((ext_vector_type(8))) unsigned short u16x8;

__device__ __forceinline__ unsigned short f2bf(float f) {
    unsigned u = __builtin_bit_cast(unsigned, f);
    return (unsigned short)((u + 0x7fffu + ((u >> 16) & 1u)) >> 16);  // RNE
}

__device__ __forceinline__ void glds16(const void* g, void* l) {
    __builtin_amdgcn_global_load_lds(
        (const __attribute__((address_space(1))) unsigned int*)(uintptr_t)g,
        (__attribute__((address_space(3))) unsigned int*)l, 16, 0, 0);
}

#define VMCNT(n) asm volatile("s_waitcnt vmcnt(" #n ")" ::: "memory")
#define BAR()                                  \
    do {                                       \
        asm volatile("" ::: "memory");         \
        __builtin_amdgcn_s_barrier();          \
        asm volatile("" ::: "memory");         \
    } while (0)

// ---------------------------------------------------------------------------
// Kernel 1: build G01[b][a0a1][o01][q] = F0[a0,o0,r0]*F1[a1,o1,r1]   (q=r0*2+r1)
//           and H23[b][o23][a2a3][q] = sum_{r2,r3} F2[a2,o2,r2]*F3[a3,o3,r3]
//                                      * core_flat[b, r3*8+r2*4+r1*2+r0]
// ---------------------------------------------------------------------------
__global__ __launch_bounds__(256) void prep_tables(const float* __restrict__ factors,
                                                   const float* __restrict__ cores,
                                                   float* __restrict__ G01,
                                                   float* __restrict__ H23) {
    int idx = blockIdx.x * 256 + threadIdx.x;   // 0 .. 131071
    if (idx < 65536) {
        int q = idx & 3, o01 = (idx >> 2) & 63, a01 = (idx >> 8) & 63, b = idx >> 14;
        int r0 = q >> 1, r1 = q & 1;
        int o0 = o01 >> 3, o1 = o01 & 7, a0 = a01 >> 3, a1 = a01 & 7;
        G01[idx] = factors[b*512 +   0 + a0*16 + o0*2 + r0]
                 * factors[b*512 + 128 + a1*16 + o1*2 + r1];
    } else {
        int j = idx - 65536;
        int q = j & 3, a23 = (j >> 2) & 63, o23 = (j >> 8) & 63, b = j >> 14;
        int r0 = q >> 1, r1 = q & 1;
        int o2 = o23 >> 3, o3 = o23 & 7, a2 = a23 >> 3, a3 = a23 & 7;
        float s = 0.f;
#pragma unroll
        for (int r2 = 0; r2 < 2; ++r2)
#pragma unroll
            for (int r3 = 0; r3 < 2; ++r3)
                s += factors[b*512 + 256 + a2*16 + o2*2 + r2]
                   * factors[b*512 + 384 + a3*16 + o3*2 + r3]
                   * cores[b*16 + r3*8 + r2*4 + r1*2 + r0];
        H23[j] = s;   // j == ((b*64 + o23)*64 + a23)*4 + q
    }
}

// ---------------------------------------------------------------------------
// Kernel 2: convert x (f32) -> bf16
// ---------------------------------------------------------------------------
__global__ __launch_bounds__(256) void cvt_bf16(const float4* __restrict__ in,
                                                ushort4* __restrict__ out) {
    int i = blockIdx.x * 256 + threadIdx.x;     // exactly 1048576 threads
    float4 v = in[i];
    ushort4 o;
    o.x = f2bf(v.x); o.y = f2bf(v.y); o.z = f2bf(v.z); o.w = f2bf(v.w);
    out[i] = o;
}

// ---------------------------------------------------------------------------
// Kernel 3: Wt[o][i] (bf16), o = o01*64+o23, i = a01*64+a23.
// LDS-buffered output, coalesced 16B stores.
// ---------------------------------------------------------------------------
__global__ __launch_bounds__(256) void build_w(const float* __restrict__ G01,
                                               const float* __restrict__ H23,
                                               unsigned short* __restrict__ Wt) {
    __shared__ float gs[2048];                   // [b][a'(2)][o01(64)][q(4)]
    __shared__ unsigned short lbuf[256 * 128];   // [o-row(256)][i-col(128)]
    const int bid = blockIdx.x;
    const int pgrp = bid & 15, lgrp = bid >> 4;  // lgrp 0..31
    const int tid = threadIdx.x;
#pragma unroll
    for (int rep = 0; rep < 2; ++rep) {
        int j = (rep * 256 + tid) * 4;
        int b = j >> 9, a = (j >> 8) & 1, rest = j & 255;
        *(float4*)&gs[j] = *(const float4*)&G01[((b * 64 + lgrp * 2 + a) << 8) + rest];
    }
    __syncthreads();
    const int o23l = tid >> 6;                   // 0..3
    const int o23 = pgrp * 4 + o23l;
    const int a23 = tid & 63;
    const float4 h0 = *(const float4*)&H23[(( 0 + o23) * 64 + a23) * 4];
    const float4 h1 = *(const float4*)&H23[((64 + o23) * 64 + a23) * 4];
    const float4 h2 = *(const float4*)&H23[((128 + o23) * 64 + a23) * 4];
    const float4 h3 = *(const float4*)&H23[((192 + o23) * 64 + a23) * 4];
    for (int it = 0; it < 128; ++it) {
        int a = it >> 6, o01 = it & 63;
        const float* gp = &gs[a * 256 + (o01 << 2)];
        float v = gp[0]    * h0.x + gp[1]    * h0.y + gp[2]    * h0.z + gp[3]    * h0.w
                + gp[512]  * h1.x + gp[513]  * h1.y + gp[514]  * h1.z + gp[515]  * h1.w
                + gp[1024] * h2.x + gp[1025] * h2.y + gp[1026] * h2.z + gp[1027] * h2.w
                + gp[1536] * h3.x + gp[1537] * h3.y + gp[1538] * h3.z + gp[1539] * h3.w;
        lbuf[(o01 * 4 + o23l) * 128 + a * 64 + a23] = f2bf(v);
    }
    __syncthreads();
#pragma unroll
    for (int j = 0; j < 16; ++j) {
        int ch = j * 256 + tid;
        int row = ch >> 4, cc = ch & 15;
        int o = (row >> 2) * 64 + pgrp * 4 + (row & 3);
        *(u16x8*)&Wt[(size_t)o * 4096 + lgrp * 128 + cc * 8] =
            *(const u16x8*)&lbuf[row * 128 + cc * 8];
    }
}

// ---------------------------------------------------------------------------
// Kernel 4: C[1024][4096] = A[1024][4096] * Wt^T.  v4:
//   tile 128x128, BK=64, 4 waves (2x2), wave-tile 64x64, acc 4x4.
//   Explicit double-buffered LDS (2 x 32KB) + RAW s_barrier + counted
//   s_waitcnt vmcnt(8): next tile's 8 global_load_lds stay in flight across
//   the barrier while current tile computes (T3/T4 minimum form).
//   No split-K (grid 256 = 1 block/CU), plain-store epilogue, no atomics.
//   Source-side XOR chunk swizzle (key (row>>1)&7 over 8 chunks/row) keeps
//   ds_read_b128 conflict-free; glds16 dest stays linear (rule 21).
// ---------------------------------------------------------------------------
__global__ __launch_bounds__(256) void gemm_bt(const unsigned short* __restrict__ A,
                                               const unsigned short* __restrict__ Bt,
                                               float* __restrict__ C) {
    constexpr int K = 4096;
    constexpr int N = 4096;
    constexpr int BK = 64;
    constexpr int NT = K / BK;                   // 64 K-steps
    __shared__ alignas(16) char lds[2][32768];   // [buf][A 16KB | B 16KB]
    const int tid = threadIdx.x;
    const int lane = tid & 63, w = tid >> 6;
    const int wm = w >> 1, wn = w & 1;
    // bijective XCD swizzle: nwg=256 -> 32 contiguous tiles per XCD
    const int wg = (blockIdx.x & 7) * 32 + (blockIdx.x >> 3);
    const int bm = wg >> 5, bn = wg & 31;

    // --- staging geometry: per tile A=1024 16B slots, B=1024; 4+4 per thread ---
    // slot cs: row = cs>>3 (8 chunks per 128B row), phys chunk p = cs&7,
    // fetched logical chunk c = p ^ ((row>>1)&7)
    const unsigned short* gA[4]; const unsigned short* gB[4];
    int lAoff[4], lBoff[4];
#pragma unroll
    for (int i = 0; i < 4; ++i) {
        int cs = w * 256 + i * 64 + lane;
        int row = cs >> 3;
        int c = (cs & 7) ^ ((row >> 1) & 7);
        gA[i] = A  + (size_t)(bm * 128 + row) * K + c * 8;
        gB[i] = Bt + (size_t)(bn * 128 + row) * K + c * 8;
        lAoff[i] = (w * 256 + i * 64) * 16;          // byte offset in A region
        lBoff[i] = 16384 + (w * 256 + i * 64) * 16;  // byte offset in B region
    }

#define STAGE(buf, kt)                                            \
    do {                                                          \
        _Pragma("unroll")                                         \
        for (int i = 0; i < 4; ++i) glds16(gA[i] + (kt), &lds[buf][lAoff[i]]); \
        _Pragma("unroll")                                         \
        for (int i = 0; i < 4; ++i) glds16(gB[i] + (kt), &lds[buf][lBoff[i]]); \
    } while (0)

    // --- fragment read offsets (swizzled): frag (m|n, kk) logical chunk kk*4+fh
    const int fr = lane & 15, fh = lane >> 4;
    const int sk = (fr >> 1) & 7;
    int aoff[2][4], boff[2][4];
#pragma unroll
    for (int kk = 0; kk < 2; ++kk)
#pragma unroll
        for (int m = 0; m < 4; ++m) {
            aoff[kk][m] = (wm * 64 + m * 16 + fr) * 128 + (((kk * 4 + fh) ^ sk) << 4);
            boff[kk][m] = 16384 + (wn * 64 + m * 16 + fr) * 128 + (((kk * 4 + fh) ^ sk) << 4);
        }

    f32x4 acc[4][4] = {};

#define COMPUTE(buf)                                                          \
    do {                                                                      \
        const char* base = &lds[buf][0];                                      \
        bf16x8 af[2][4], bfr[2][4];                                           \
        _Pragma("unroll")                                                     \
        for (int kk = 0; kk < 2; ++kk)                                        \
            _Pragma("unroll")                                                 \
            for (int m = 0; m < 4; ++m) {                                     \
                af[kk][m]  = *(const bf16x8*)(base + aoff[kk][m]);            \
                bfr[kk][m] = *(const bf16x8*)(base + boff[kk][m]);            \
            }                                                                 \
        _Pragma("unroll")                                                     \
        for (int kk = 0; kk < 2; ++kk)                                        \
            _Pragma("unroll")                                                 \
            for (int m = 0; m < 4; ++m)                                       \
                _Pragma("unroll")                                             \
                for (int n = 0; n < 4; ++n)                                   \
                    acc[m][n] = __builtin_amdgcn_mfma_f32_16x16x32_bf16(      \
                        af[kk][m], bfr[kk][n], acc[m][n], 0, 0, 0);           \
    } while (0)

    // --- pipelined main loop: 1 tile prefetch depth, counted vmcnt ---
    STAGE(0, 0);
    int cur = 0;
    for (int t = 0; t < NT - 1; ++t) {
        STAGE(cur ^ 1, (t + 1) * BK);   // 8 loads in flight across the barrier
        VMCNT(8);                        // previous tile's 8 loads complete
        BAR();                           // all waves' loads for buf[cur] landed
        COMPUTE(cur);
        BAR();                           // all waves done reading buf[cur]
        cur ^= 1;
    }
    VMCNT(0);
    BAR();
    COMPUTE(cur);

    // --- epilogue: plain coalesced stores ---
    const int crow0 = bm * 128 + wm * 64 + fh * 4;
    const int ccol0 = bn * 128 + wn * 64 + fr;
#pragma unroll
    for (int m = 0; m < 4; ++m)
#pragma unroll
        for (int n = 0; n < 4; ++n)
#pragma unroll
            for (int j = 0; j < 4; ++j)
                C[(size_t)(crow0 + m * 16 + j) * N + (ccol0 + n * 16)] = acc[m][n][j];
#undef STAGE
#undef COMPUTE
}

// ---------------------------------------------------------------------------
extern "C" void kernel_launch(void* const* d_in, const int* in_sizes, int n_in,
                              void* d_out, int out_size, void* d_ws, size_t ws_size,
                              hipStream_t stream) {
    const float* inputs  = (const float*)d_in[0];   // [1024, 4096] f32
    const float* cores   = (const float*)d_in[1];   // [4, 16] f32
    const float* factors = (const float*)d_in[2];   // [4,4,8,8,2] f32
    float* out = (float*)d_out;                     // [1024, 4096] f32

    char* ws = (char*)d_ws;
    unsigned short* xb = (unsigned short*)ws;                       //  8 MB bf16 x
    unsigned short* Wt = (unsigned short*)(ws + (8u << 20));        // 32 MB bf16 W^T
    float* G01 = (float*)(ws + (40u << 20));                        // 256 KB
    float* H23 = G01 + 65536;                                       // 256 KB

    prep_tables<<<512, 256, 0, stream>>>(factors, cores, G01, H23);
    cvt_bf16<<<4096, 256, 0, stream>>>((const float4*)inputs, (ushort4*)xb);
    build_w<<<512, 256, 0, stream>>>(G01, H23, Wt);
    gemm_bt<<<256, 256, 0, stream>>>(xb, Wt, out);
}

// Round 5
// 76.419 us; speedup vs baseline: 1.8082x; 1.1416x over previous
//
#include <hip/hip_runtime.h>
#include <hip/hip_bf16.h>
#include <stdint.h>

typedef __attribute__((ext_vector_type(8))) __bf16 bf16x8;
typedef __attribute__((ext_vector_type(4))) float f32x4;
typedef __attribute__((ext_vector_type(8))) unsigned short u16x8;

__device__ __forceinline__ unsigned short f2bf(float f) {
    unsigned u = __builtin_bit_cast(unsigned, f);
    return (unsigned short)((u + 0x7fffu + ((u >> 16) & 1u)) >> 16);  // RNE
}

__device__ __forceinline__ void glds16(const void* g, void* l) {
    __builtin_amdgcn_global_load_lds(
        (const __attribute__((address_space(1))) unsigned int*)(uintptr_t)g,
        (__attribute__((address_space(3))) unsigned int*)l, 16, 0, 0);
}

#define VMCNT(n) asm volatile("s_waitcnt vmcnt(" #n ")" ::: "memory")
#define BAR()                                  \
    do {                                       \
        asm volatile("" ::: "memory");         \
        __builtin_amdgcn_s_barrier();          \
        asm volatile("" ::: "memory");         \
    } while (0)

// ---------------------------------------------------------------------------
// Kernel 1: build MFMA-ready slabs for the W-construction GEMM (K=16, 0-padded
// to 32).  W in permuted space: W[(o01,o23)][(a01,a23)] = sum_k A'[m][k]B'[n][k]
//   Aslab[bo][m][32]: m = o01l*64+a01 (o01 = bo*4+o01l), k = b*4+q,
//        val = F0[a0,o0,r0]*F1[a1,o1,r1]
//   Bslab[bn4][n][32]: n = o23l*64+a23, val = sum_{r2,r3} F2*F3*core
// factors layout: [b][j][i][o][r] strides b:512 j:128 i:16 o:2 r:1
// ---------------------------------------------------------------------------
__global__ __launch_bounds__(256) void prep_slabs(const float* __restrict__ factors,
                                                  const float* __restrict__ cores,
                                                  unsigned short* __restrict__ Aslab,
                                                  unsigned short* __restrict__ Bslab) {
    int idx = blockIdx.x * 256 + threadIdx.x;   // 0 .. 131071
    int e = idx & 65535;
    int grp = e >> 12;                           // bo or bn4 (0..15)
    int m = (e >> 4) & 255;                      // row in slab
    int k = e & 15;                              // (b,q)
    int b = k >> 2, q = k & 3, r0 = q >> 1, r1 = q & 1;
    int base = (e >> 4) * 32;
    if (idx < 65536) {
        int o01 = grp * 4 + (m >> 6), a01 = m & 63;
        int o0 = o01 >> 3, o1 = o01 & 7, a0 = a01 >> 3, a1 = a01 & 7;
        float v = factors[b*512 +   0 + a0*16 + o0*2 + r0]
                * factors[b*512 + 128 + a1*16 + o1*2 + r1];
        Aslab[base + k] = f2bf(v);
        Aslab[base + k + 16] = 0;
    } else {
        int o23 = grp * 4 + (m >> 6), a23 = m & 63;
        int o2 = o23 >> 3, o3 = o23 & 7, a2 = a23 >> 3, a3 = a23 & 7;
        float s = 0.f;
#pragma unroll
        for (int r2 = 0; r2 < 2; ++r2)
#pragma unroll
            for (int r3 = 0; r3 < 2; ++r3)
                s += factors[b*512 + 256 + a2*16 + o2*2 + r2]
                   * factors[b*512 + 384 + a3*16 + o3*2 + r3]
                   * cores[b*16 + r3*8 + r2*4 + r1*2 + r0];
        Bslab[base + k] = f2bf(s);
        Bslab[base + k + 16] = 0;
    }
}

// ---------------------------------------------------------------------------
// Kernel 2: convert x (f32) -> bf16
// ---------------------------------------------------------------------------
__global__ __launch_bounds__(256) void cvt_bf16(const float4* __restrict__ in,
                                                ushort4* __restrict__ out) {
    int i = blockIdx.x * 256 + threadIdx.x;     // exactly 1048576 threads
    float4 v = in[i];
    ushort4 o;
    o.x = f2bf(v.x); o.y = f2bf(v.y); o.z = f2bf(v.z); o.w = f2bf(v.w);
    out[i] = o;
}

// ---------------------------------------------------------------------------
// Kernel 3: W build as 4096x4096x16 MFMA GEMM (K padded to 32).
// Grid 256: block (bo,bn4) computes the 256x256 permuted patch = 16 COMPLETE
// W rows o=(bo*4+w)*64 + bn4*4+wn, each 4096 cols contiguous (8 KB bf16).
// Wave w: A-rows w*64..+64 (4 frags, reused), 4 n-subtiles wn, 16 MFMA each.
// Epilogue: per-wave 64x64 patch -> padded LDS buf -> coalesced 16B stores.
// ---------------------------------------------------------------------------
__global__ __launch_bounds__(256) void build_w2(const unsigned short* __restrict__ Aslab,
                                                const unsigned short* __restrict__ Bslab,
                                                unsigned short* __restrict__ Wt) {
    __shared__ unsigned short As2[256 * 40];     // rows padded to 40 elems (80 B)
    __shared__ unsigned short Bs2[256 * 40];
    __shared__ unsigned short lbuf[4 * 64 * 72]; // per-wave 64 x 72(pad) patch
    const int tid = threadIdx.x, lane = tid & 63, w = tid >> 6;
    const int bo = blockIdx.x >> 4, bn4 = blockIdx.x & 15;

    const u16x8* srcA = (const u16x8*)(Aslab + ((size_t)bo * 256 + tid) * 32);
    const u16x8* srcB = (const u16x8*)(Bslab + ((size_t)bn4 * 256 + tid) * 32);
#pragma unroll
    for (int i = 0; i < 4; ++i) {
        *(u16x8*)&As2[tid * 40 + i * 8] = srcA[i];
        *(u16x8*)&Bs2[tid * 40 + i * 8] = srcB[i];
    }
    __syncthreads();

    const int fr = lane & 15, fh = lane >> 4;
    bf16x8 af[4];
#pragma unroll
    for (int mf = 0; mf < 4; ++mf)
        af[mf] = *(const bf16x8*)&As2[(w * 64 + mf * 16 + fr) * 40 + fh * 8];

    for (int wn = 0; wn < 4; ++wn) {
        f32x4 acc[4][4] = {};
        bf16x8 bf_[4];
#pragma unroll
        for (int nf = 0; nf < 4; ++nf)
            bf_[nf] = *(const bf16x8*)&Bs2[(wn * 64 + nf * 16 + fr) * 40 + fh * 8];
#pragma unroll
        for (int mf = 0; mf < 4; ++mf)
#pragma unroll
            for (int nf = 0; nf < 4; ++nf)
                acc[mf][nf] = __builtin_amdgcn_mfma_f32_16x16x32_bf16(
                    af[mf], bf_[nf], acc[mf][nf], 0, 0, 0);
#pragma unroll
        for (int mf = 0; mf < 4; ++mf)
#pragma unroll
            for (int nf = 0; nf < 4; ++nf)
#pragma unroll
                for (int j = 0; j < 4; ++j)
                    lbuf[w * 4608 + (mf * 16 + fh * 4 + j) * 72 + nf * 16 + fr] =
                        f2bf(acc[mf][nf][j]);
        // same-wave LDS RAW: compiler inserts lgkmcnt waits
        const int o = (bo * 4 + w) * 64 + bn4 * 4 + wn;
        unsigned short* dst = Wt + (size_t)o * 4096;
#pragma unroll
        for (int i = 0; i < 8; ++i) {
            int c = i * 64 + lane;               // 16B chunk 0..511 of the row
            *(u16x8*)&dst[c * 8] =
                *(const u16x8*)&lbuf[w * 4608 + (c >> 3) * 72 + (c & 7) * 8];
        }
    }
}

// ---------------------------------------------------------------------------
// Kernel 4: C[1024][4096] = A[1024][4096] * Wt^T.  v5:
//   128x128 tile, BK=64, 4 waves (2x2), 16x16x32 MFMA, grid 256 (1/CU).
//   XCD mapping: each XCD owns a bn-QUAD (4 MB of W stays L2-resident);
//   A (8 MB) streams via L3.  (R4 mapping streamed all 32 MB of W through
//   every XCD's L2 -> 512 MB delivery bound, FETCH 135 MB.)
//   Depth-2 pipeline: 4 LDS buffers, counted s_waitcnt vmcnt(16), raw
//   s_barrier; never drains vmcnt to 0 in the main loop.
//   Source-side XOR chunk swizzle keeps ds_read_b128 conflict-free (rule 21).
// ---------------------------------------------------------------------------
__global__ __launch_bounds__(256) void gemm_bt(const unsigned short* __restrict__ A,
                                               const unsigned short* __restrict__ Bt,
                                               float* __restrict__ C) {
    constexpr int K = 4096;
    constexpr int N = 4096;
    constexpr int BK = 64;
    constexpr int NT = K / BK;                   // 64 K-steps
    __shared__ alignas(16) char lds[4][32768];   // [buf][A 16KB | B 16KB]
    const int tid = threadIdx.x;
    const int lane = tid & 63, w = tid >> 6;
    const int wm = w >> 1, wn = w & 1;
    // XCD-quad mapping: xcd = blockIdx%8 owns bn in [xcd*4, xcd*4+4)
    const int xcd = blockIdx.x & 7, idx = blockIdx.x >> 3;   // idx 0..31
    const int bn = xcd * 4 + (idx & 3);
    const int bm = idx >> 2;                     // 0..7

    // staging: slot cs -> row = cs>>3, phys chunk p = cs&7, fetch c = p^((row>>1)&7)
    const unsigned short* gA[4]; const unsigned short* gB[4];
    int lAoff[4], lBoff[4];
#pragma unroll
    for (int i = 0; i < 4; ++i) {
        int cs = w * 256 + i * 64 + lane;
        int row = cs >> 3;
        int c = (cs & 7) ^ ((row >> 1) & 7);
        gA[i] = A  + (size_t)(bm * 128 + row) * K + c * 8;
        gB[i] = Bt + (size_t)(bn * 128 + row) * K + c * 8;
        lAoff[i] = (w * 256 + i * 64) * 16;
        lBoff[i] = 16384 + (w * 256 + i * 64) * 16;
    }

#define STAGE(buf, kt)                                            \
    do {                                                          \
        _Pragma("unroll")                                         \
        for (int i = 0; i < 4; ++i) glds16(gA[i] + (kt), &lds[buf][lAoff[i]]); \
        _Pragma("unroll")                                         \
        for (int i = 0; i < 4; ++i) glds16(gB[i] + (kt), &lds[buf][lBoff[i]]); \
    } while (0)

    const int fr = lane & 15, fh = lane >> 4;
    const int sk = (fr >> 1) & 7;
    int aoff[2][4], boff[2][4];
#pragma unroll
    for (int kk = 0; kk < 2; ++kk)
#pragma unroll
        for (int m = 0; m < 4; ++m) {
            aoff[kk][m] = (wm * 64 + m * 16 + fr) * 128 + (((kk * 4 + fh) ^ sk) << 4);
            boff[kk][m] = 16384 + (wn * 64 + m * 16 + fr) * 128 + (((kk * 4 + fh) ^ sk) << 4);
        }

    f32x4 acc[4][4] = {};

#define COMPUTE(buf)                                                          \
    do {                                                                      \
        const char* base = &lds[buf][0];                                      \
        bf16x8 af[2][4], bfr[2][4];                                           \
        _Pragma("unroll")                                                     \
        for (int kk = 0; kk < 2; ++kk)                                        \
            _Pragma("unroll")                                                 \
            for (int m = 0; m < 4; ++m) {                                     \
                af[kk][m]  = *(const bf16x8*)(base + aoff[kk][m]);            \
                bfr[kk][m] = *(const bf16x8*)(base + boff[kk][m]);            \
            }                                                                 \
        _Pragma("unroll")                                                     \
        for (int kk = 0; kk < 2; ++kk)                                        \
            _Pragma("unroll")                                                 \
            for (int m = 0; m < 4; ++m)                                       \
                _Pragma("unroll")                                             \
                for (int n = 0; n < 4; ++n)                                   \
                    acc[m][n] = __builtin_amdgcn_mfma_f32_16x16x32_bf16(      \
                        af[kk][m], bfr[kk][n], acc[m][n], 0, 0, 0);           \
    } while (0)

    // --- depth-2 pipelined loop ---
    STAGE(0, 0);
    STAGE(1, BK);
    for (int t = 0; t < NT - 2; ++t) {
        STAGE((t + 2) & 3, (t + 2) * BK);  // 24 in flight
        VMCNT(16);                          // tile t's 8 loads complete
        BAR();
        COMPUTE(t & 3);
        BAR();                              // readers done before next STAGE
    }
    VMCNT(8);  BAR(); COMPUTE((NT - 2) & 3); BAR();
    VMCNT(0);  BAR(); COMPUTE((NT - 1) & 3);

    const int crow0 = bm * 128 + wm * 64 + fh * 4;
    const int ccol0 = bn * 128 + wn * 64 + fr;
#pragma unroll
    for (int m = 0; m < 4; ++m)
#pragma unroll
        for (int n = 0; n < 4; ++n)
#pragma unroll
            for (int j = 0; j < 4; ++j)
                C[(size_t)(crow0 + m * 16 + j) * N + (ccol0 + n * 16)] = acc[m][n][j];
#undef STAGE
#undef COMPUTE
}

// ---------------------------------------------------------------------------
extern "C" void kernel_launch(void* const* d_in, const int* in_sizes, int n_in,
                              void* d_out, int out_size, void* d_ws, size_t ws_size,
                              hipStream_t stream) {
    const float* inputs  = (const float*)d_in[0];   // [1024, 4096] f32
    const float* cores   = (const float*)d_in[1];   // [4, 16] f32
    const float* factors = (const float*)d_in[2];   // [4,4,8,8,2] f32
    float* out = (float*)d_out;                     // [1024, 4096] f32

    char* ws = (char*)d_ws;
    unsigned short* xb    = (unsigned short*)ws;                    //  8 MB bf16 x
    unsigned short* Wt    = (unsigned short*)(ws + (8u << 20));     // 32 MB bf16 W^T
    unsigned short* Aslab = (unsigned short*)(ws + (40u << 20));    // 256 KB
    unsigned short* Bslab = Aslab + 131072;                         // 256 KB

    prep_slabs<<<512, 256, 0, stream>>>(factors, cores, Aslab, Bslab);
    cvt_bf16<<<4096, 256, 0, stream>>>((const float4*)inputs, (ushort4*)xb);
    build_w2<<<256, 256, 0, stream>>>(Aslab, Bslab, Wt);
    gemm_bt<<<256, 256, 0, stream>>>(xb, Wt, out);
}